// Round 4
// baseline (465.879 us; speedup 1.0000x reference)
//
#include <hip/hip_runtime.h>
#include <hip/hip_bf16.h>
#include <math.h>

// NoisyTopkRouter: B=4, S=4096, D=2048, E=64, K=8
// logits = x@W_route + b_route ; noise_logits = x@W_noise + b_noise
// noisy = logits + noise * softplus(noise_logits)
// top8 (descending, ties -> lower index), softmax over top8, scatter to [B,S,E]
// Outputs (flat f32 in d_out): [B*S*E] probs, then [B*S*8] indices as floats.
//
// Design: wave-per-8-rows, lane = expert (64 lanes = 64 experts).
//  - x rows are wave-uniform -> scalar loads (s_load) feed v_fmac as SGPR operand
//  - W_route/W_noise stream as 64-lane coalesced 256B lines (L1-reused by all waves)
//  - no LDS, no barriers; f32 chunk accumulation + f64 totals for precision
//  - fused epilogue: butterfly top-8 argmax via __shfl_xor, softmax, scatter

#define BD 2048   // D
#define BE 64     // E
#define RPW 8     // rows per wave
#define WPB 4     // waves per block
#define ROWS_PER_BLOCK (RPW * WPB)

__global__ __launch_bounds__(256, 2)
void noisy_topk_router(const float* __restrict__ x,
                       const float* __restrict__ noise,
                       const float* __restrict__ Wr,
                       const float* __restrict__ brp,
                       const float* __restrict__ Wn,
                       const float* __restrict__ bnp,
                       float* __restrict__ out,
                       int BS)
{
    const int lane = threadIdx.x & 63;
    const int wave = threadIdx.x >> 6;
    // force wave-uniform row base into SGPR so x loads become scalar loads
    const int m0 = __builtin_amdgcn_readfirstlane(blockIdx.x * ROWS_PER_BLOCK + wave * RPW);
    const float* xbase = x + (size_t)m0 * BD;

    const float brv = brp[lane];
    const float bnv = bnp[lane];

    double tr[RPW], tn[RPW];
#pragma unroll
    for (int i = 0; i < RPW; ++i) { tr[i] = 0.0; tn[i] = 0.0; }

    for (int dc = 0; dc < BD; dc += 128) {
        float ar[RPW], an[RPW];
#pragma unroll
        for (int i = 0; i < RPW; ++i) { ar[i] = 0.f; an[i] = 0.f; }
#pragma unroll 2
        for (int d = dc; d < dc + 128; d += 4) {
            float4 xv[RPW];
#pragma unroll
            for (int i = 0; i < RPW; ++i)
                xv[i] = *reinterpret_cast<const float4*>(xbase + (size_t)i * BD + d);
#pragma unroll
            for (int k = 0; k < 4; ++k) {
                const float wr = Wr[(d + k) * BE + lane];
                const float wn = Wn[(d + k) * BE + lane];
#pragma unroll
                for (int i = 0; i < RPW; ++i) {
                    const float xs = (k == 0) ? xv[i].x : (k == 1) ? xv[i].y
                                   : (k == 2) ? xv[i].z : xv[i].w;
                    ar[i] = fmaf(xs, wr, ar[i]);
                    an[i] = fmaf(xs, wn, an[i]);
                }
            }
        }
#pragma unroll
        for (int i = 0; i < RPW; ++i) { tr[i] += (double)ar[i]; tn[i] += (double)an[i]; }
    }

    const size_t P = (size_t)BS * BE;  // start of index region in d_out

#pragma unroll 1
    for (int i = 0; i < RPW; ++i) {
        const int row = m0 + i;
        const float vr = (float)tr[i] + brv;
        const float vn = (float)tn[i] + bnv;
        const float nz = noise[(size_t)row * BE + lane];
        // stable softplus, same form as jax.nn.softplus == logaddexp(x, 0)
        const float sp  = fmaxf(vn, 0.f) + log1pf(expf(-fabsf(vn)));
        const float val = fmaf(nz, sp, vr);

        // top-8 via 8 butterfly argmax passes (ties -> lower index, lax.top_k order)
        float cur = val;
        float bv_a[8];
        int   bi_a[8];
#pragma unroll
        for (int j = 0; j < 8; ++j) {
            float bv = cur;
            int   bi = lane;
#pragma unroll
            for (int off = 32; off > 0; off >>= 1) {
                const float ov = __shfl_xor(bv, off);
                const int   oi = __shfl_xor(bi, off);
                if (ov > bv || (ov == bv && oi < bi)) { bv = ov; bi = oi; }
            }
            bv_a[j] = bv;
            bi_a[j] = bi;
            if (lane == bi) cur = -INFINITY;  // exclude winner
        }

        // softmax over the 8 selected values (max is bv_a[0])
        const float mx = bv_a[0];
        float p[8];
        float s = 0.f;
#pragma unroll
        for (int j = 0; j < 8; ++j) { p[j] = expf(bv_a[j] - mx); s += p[j]; }

        float myp = 0.f;
#pragma unroll
        for (int j = 0; j < 8; ++j) { if (bi_a[j] == lane) myp = p[j] / s; }

        out[(size_t)row * BE + lane] = myp;
        // indices written as float values (harness reads flat d_out as f32)
#pragma unroll
        for (int j = 0; j < 8; ++j) {
            if (lane == j) out[P + (size_t)row * 8 + j] = (float)bi_a[j];
        }
    }
}

extern "C" void kernel_launch(void* const* d_in, const int* in_sizes, int n_in,
                              void* d_out, int out_size, void* d_ws, size_t ws_size,
                              hipStream_t stream) {
    (void)n_in; (void)d_ws; (void)ws_size; (void)out_size;
    const float* x     = (const float*)d_in[0];
    const float* noise = (const float*)d_in[1];
    const float* Wr    = (const float*)d_in[2];
    const float* br    = (const float*)d_in[3];
    const float* Wn    = (const float*)d_in[4];
    const float* bn    = (const float*)d_in[5];
    float* out = (float*)d_out;

    const int BS = in_sizes[1] / BE;          // B*S = 16384
    const int blocks = BS / ROWS_PER_BLOCK;   // 512
    noisy_topk_router<<<blocks, 256, 0, stream>>>(x, noise, Wr, br, Wn, bn, out, BS);
}

// Round 6
// 446.305 us; speedup vs baseline: 1.0439x; 1.0439x over previous
//
#include <hip/hip_runtime.h>
#include <hip/hip_bf16.h>
#include <math.h>

// NoisyTopkRouter: B=4, S=4096, D=2048, E=64, K=8
// Round 5: split-K x4 for occupancy. R4 data: VALUBusy 41%, Occ 22%,
// 330us; VALU-busy time (135us) == FMA floor + overhead, so the gap is
// unhidden latency at 2 waves/SIMD. Keep RPW=8 (VALU:L1 = 2:1), split
// D=2048 over the 4 waves of each block (512 d each) -> 8192 waves =
// 8/SIMD. Combine f32 partials in LDS (error 3e-8 << existing 3e-7
// chunk-accum err), f64 combine, epilogue 2 rows/wave.

#define BD 2048   // D
#define BE 64     // E
#define RPB 8     // rows per block (= rows per wave in the GEMV phase)
#define NW 4      // waves per block = K-split factor
#define DPW (BD / NW)  // 512 d-values per wave

__global__ __launch_bounds__(256, 8)
void noisy_topk_router(const float* __restrict__ x,
                       const float* __restrict__ noise,
                       const float* __restrict__ Wr,
                       const float* __restrict__ brp,
                       const float* __restrict__ Wn,
                       const float* __restrict__ bnp,
                       float* __restrict__ out,
                       int BS)
{
    const int lane = threadIdx.x & 63;
    const int wave = __builtin_amdgcn_readfirstlane(threadIdx.x >> 6);
    const int m0   = __builtin_amdgcn_readfirstlane(blockIdx.x * RPB);
    const int d0   = wave * DPW;
    // wave-uniform x base -> scalar loads (s_load) feed v_fmac as SGPR operand
    const float* xbase = x + (size_t)m0 * BD + d0;

    __shared__ float pr[NW][RPB][BE];
    __shared__ float pn[NW][RPB][BE];

    double tr[RPB], tn[RPB];
#pragma unroll
    for (int i = 0; i < RPB; ++i) { tr[i] = 0.0; tn[i] = 0.0; }

    for (int dc = 0; dc < DPW; dc += 128) {
        float ar[RPB], an[RPB];
#pragma unroll
        for (int i = 0; i < RPB; ++i) { ar[i] = 0.f; an[i] = 0.f; }
#pragma unroll 2
        for (int d = dc; d < dc + 128; d += 4) {
            float4 xv[RPB];
#pragma unroll
            for (int i = 0; i < RPB; ++i)
                xv[i] = *reinterpret_cast<const float4*>(xbase + (size_t)i * BD + d);
#pragma unroll
            for (int k = 0; k < 4; ++k) {
                const float wr = Wr[(size_t)(d0 + d + k) * BE + lane];
                const float wn = Wn[(size_t)(d0 + d + k) * BE + lane];
#pragma unroll
                for (int i = 0; i < RPB; ++i) {
                    const float xs = (k == 0) ? xv[i].x : (k == 1) ? xv[i].y
                                   : (k == 2) ? xv[i].z : xv[i].w;
                    ar[i] = fmaf(xs, wr, ar[i]);
                    an[i] = fmaf(xs, wn, an[i]);
                }
            }
        }
#pragma unroll
        for (int i = 0; i < RPB; ++i) { tr[i] += (double)ar[i]; tn[i] += (double)an[i]; }
    }

    // publish f32 partials (rounding err ~3e-8, negligible vs chunk accum)
#pragma unroll
    for (int i = 0; i < RPB; ++i) {
        pr[wave][i][lane] = (float)tr[i];
        pn[wave][i][lane] = (float)tn[i];
    }
    __syncthreads();

    const float brv = brp[lane];
    const float bnv = bnp[lane];
    const size_t P = (size_t)BS * BE;  // start of index region in d_out

    // epilogue: each wave finishes 2 rows
#pragma unroll 1
    for (int ii = 0; ii < RPB / NW; ++ii) {
        const int rl  = wave * (RPB / NW) + ii;
        const int row = m0 + rl;

        double sr = 0.0, sn = 0.0;
#pragma unroll
        for (int w = 0; w < NW; ++w) { sr += (double)pr[w][rl][lane]; sn += (double)pn[w][rl][lane]; }

        const float vr = (float)sr + brv;
        const float vn = (float)sn + bnv;
        const float nz = noise[(size_t)row * BE + lane];
        // stable softplus == jax.nn.softplus
        const float sp  = fmaxf(vn, 0.f) + log1pf(expf(-fabsf(vn)));
        const float val = fmaf(nz, sp, vr);

        // top-8 via 8 butterfly argmax passes (ties -> lower index)
        float cur = val;
        float bv_a[8];
        int   bi_a[8];
#pragma unroll
        for (int j = 0; j < 8; ++j) {
            float bv = cur;
            int   bi = lane;
#pragma unroll
            for (int off = 32; off > 0; off >>= 1) {
                const float ov = __shfl_xor(bv, off);
                const int   oi = __shfl_xor(bi, off);
                if (ov > bv || (ov == bv && oi < bi)) { bv = ov; bi = oi; }
            }
            bv_a[j] = bv;
            bi_a[j] = bi;
            if (lane == bi) cur = -INFINITY;  // exclude winner
        }

        // softmax over the 8 selected values (max is bv_a[0])
        const float mx = bv_a[0];
        float p[8];
        float s = 0.f;
#pragma unroll
        for (int j = 0; j < 8; ++j) { p[j] = expf(bv_a[j] - mx); s += p[j]; }

        float myp = 0.f;
#pragma unroll
        for (int j = 0; j < 8; ++j) { if (bi_a[j] == lane) myp = p[j] / s; }

        out[(size_t)row * BE + lane] = myp;
        // indices written as float values (harness reads flat d_out as f32)
#pragma unroll
        for (int j = 0; j < 8; ++j) {
            if (lane == j) out[P + (size_t)row * 8 + j] = (float)bi_a[j];
        }
    }
}

extern "C" void kernel_launch(void* const* d_in, const int* in_sizes, int n_in,
                              void* d_out, int out_size, void* d_ws, size_t ws_size,
                              hipStream_t stream) {
    (void)n_in; (void)d_ws; (void)ws_size; (void)out_size;
    const float* x     = (const float*)d_in[0];
    const float* noise = (const float*)d_in[1];
    const float* Wr    = (const float*)d_in[2];
    const float* br    = (const float*)d_in[3];
    const float* Wn    = (const float*)d_in[4];
    const float* bn    = (const float*)d_in[5];
    float* out = (float*)d_out;

    const int BS = in_sizes[1] / BE;   // B*S = 16384
    const int blocks = BS / RPB;       // 2048 blocks = 8 blocks/CU
    noisy_topk_router<<<blocks, NW * 64, 0, stream>>>(x, noise, Wr, br, Wn, bn, out, BS);
}